// Round 1
// baseline (171.211 us; speedup 1.0000x reference)
//
#include <hip/hip_runtime.h>
#include <cstddef>

// Problem constants (fixed by the reference): B=4096, T=204800, D=32, H=64
#define DICE_EPS 1e-10f

// ---------------------------------------------------------------------------
// Kernel 1: per-candidate precompute.
//   M[r][i][k] = W1[(32+i)*64+k] + sum_j cand[r][j] * W1[(64+i*32+j)*64+k]
// This is a [B x 32] @ [32 x 2048] GEMM, r-tiled by 16 so the 262 KB W1o
// slice is only re-read B/16 = 256 times (16.8 MB, L2-resident).
// ---------------------------------------------------------------------------
__global__ __launch_bounds__(256) void precompute_M(
    const float* __restrict__ cand, const float* __restrict__ W1,
    float* __restrict__ M) {
  constexpr int RT = 16;  // candidates per block
  __shared__ float cl[RT * 32];
  const int r0 = blockIdx.x * RT;
  for (int idx = threadIdx.x; idx < RT * 32; idx += 256)
    cl[idx] = cand[(size_t)r0 * 32 + idx];
  __syncthreads();

  const int k = threadIdx.x & 63;   // output column 0..63
  const int q = threadIdx.x >> 6;   // wave id 0..3 -> i block

#pragma unroll
  for (int ig = 0; ig < 2; ig++) {
    float acc[4][RT];
#pragma unroll
    for (int ii = 0; ii < 4; ii++)
#pragma unroll
      for (int r = 0; r < RT; r++) acc[ii][r] = 0.f;

    for (int j = 0; j < 32; j++) {
      float cr[RT];
#pragma unroll
      for (int r = 0; r < RT; r++) cr[r] = cl[r * 32 + j];  // LDS broadcast
#pragma unroll
      for (int ii = 0; ii < 4; ii++) {
        const int i = q * 8 + ig * 4 + ii;  // covers 0..31 disjointly
        const float wv = W1[(size_t)(64 + i * 32 + j) * 64 + k];  // coalesced
#pragma unroll
        for (int r = 0; r < RT; r++) acc[ii][r] += cr[r] * wv;
      }
    }
#pragma unroll
    for (int ii = 0; ii < 4; ii++) {
      const int i = q * 8 + ig * 4 + ii;
      const float wb = W1[(size_t)(32 + i) * 64 + k];
#pragma unroll
      for (int r = 0; r < RT; r++)
        M[(size_t)(r0 + r) * 2048 + i * 64 + k] = acc[ii][r] + wb;
    }
  }
}

// ---------------------------------------------------------------------------
// Kernel 2: one block (4 waves) per candidate r. Each wave processes one
// behavior row at a time: lane k owns h[k]; M[.][k] lives in 32 VGPRs.
// Dice + H->1 projection via 64-lane butterfly reductions.
// ---------------------------------------------------------------------------
__global__ __launch_bounds__(256) void attention_rows(
    const float* __restrict__ cand, const float* __restrict__ behavior,
    const int* __restrict__ row_ids, const float* __restrict__ W1,
    const float* __restrict__ b1, const float* __restrict__ alpha,
    const float* __restrict__ W2, const float* __restrict__ b2,
    const float* __restrict__ M, float* __restrict__ out, int T) {
  const int r = blockIdx.x;
  const int lane = threadIdx.x & 63;
  const int wid = threadIdx.x >> 6;

  // Segment bounds in sorted row_ids (uniform binary search, ~18 steps).
  int lo = 0, hi = T;
  while (lo < hi) { int mid = (lo + hi) >> 1; if (row_ids[mid] < r) lo = mid + 1; else hi = mid; }
  const int t0 = lo;
  hi = T;
  while (lo < hi) { int mid = (lo + hi) >> 1; if (row_ids[mid] < r + 1) lo = mid + 1; else hi = mid; }
  const int t1 = lo;

  // Per-lane constants: lane k's column of M, base[k], alpha[k], W2[k].
  float Mreg[32];
#pragma unroll
  for (int i = 0; i < 32; i++)
    Mreg[i] = M[(size_t)r * 2048 + i * 64 + lane];  // coalesced, L3-hot

  float base = b1[lane];
#pragma unroll
  for (int d = 0; d < 32; d++)
    base += cand[(size_t)r * 32 + d] * W1[(size_t)d * 64 + lane];
  const float al = alpha[lane];
  const float w2k = W2[lane];
  const float b2v = b2[0];

  float acc = 0.f;  // lanes 0..31 (and mirrored 32..63) accumulate out[r][d]

  for (int t = t0 + wid; t < t1; t += 4) {
    const int tu = __builtin_amdgcn_readfirstlane(t);  // wave-uniform row id
    const float* bp = behavior + (size_t)tu * 32;
    const float bvv = bp[lane & 31];  // per-lane copy for the output accum

    // Wave-uniform full bv vector (scalar-load path) for the h dot product.
    float bvarr[32];
    const float4* b4 = reinterpret_cast<const float4*>(bp);
#pragma unroll
    for (int v = 0; v < 8; v++) {
      const float4 qv = b4[v];
      bvarr[4 * v + 0] = qv.x; bvarr[4 * v + 1] = qv.y;
      bvarr[4 * v + 2] = qv.z; bvarr[4 * v + 3] = qv.w;
    }

    float h = base;
#pragma unroll
    for (int i = 0; i < 32; i++) h += bvarr[i] * Mreg[i];

    // --- Dice activation across the 64 h-values held by this wave ---
    float s = h;
#pragma unroll
    for (int off = 32; off > 0; off >>= 1) s += __shfl_xor(s, off, 64);
    const float mean = s * (1.f / 64.f);
    const float dlt = h - mean;
    float s2 = dlt * dlt;
#pragma unroll
    for (int off = 32; off > 0; off >>= 1) s2 += __shfl_xor(s2, off, 64);
    const float stdv = sqrtf(s2 * (1.f / 64.f) + DICE_EPS);  // mean(sq+eps)=meansq+eps
    const float p = 1.f / (1.f + __expf(-dlt / (stdv + DICE_EPS)));
    const float hd = al * (1.f - p) * h + p * h;

    // --- w = dice(h) @ W2 + b2 (scalar per row) ---
    float wp = hd * w2k;
#pragma unroll
    for (int off = 32; off > 0; off >>= 1) wp += __shfl_xor(wp, off, 64);
    const float w = wp + b2v;

    acc += bvv * w;  // weighted = bv * w, accumulated into the segment sum
  }

  // Combine the 4 waves' partial segment sums through LDS.
  __shared__ float sacc[4][32];
  if (lane < 32) sacc[wid][lane] = acc;
  __syncthreads();
  if (threadIdx.x < 32) {
    const float v = sacc[0][threadIdx.x] + sacc[1][threadIdx.x] +
                    sacc[2][threadIdx.x] + sacc[3][threadIdx.x];
    out[(size_t)r * 32 + threadIdx.x] = v;
  }
}

// ---------------------------------------------------------------------------
extern "C" void kernel_launch(void* const* d_in, const int* in_sizes, int n_in,
                              void* d_out, int out_size, void* d_ws, size_t ws_size,
                              hipStream_t stream) {
  const float* cand     = (const float*)d_in[0];
  const float* behavior = (const float*)d_in[1];
  const int*   row_ids  = (const int*)d_in[2];
  const float* W1       = (const float*)d_in[3];
  const float* b1       = (const float*)d_in[4];
  const float* alpha    = (const float*)d_in[5];
  const float* W2       = (const float*)d_in[6];
  const float* b2       = (const float*)d_in[7];
  float* out = (float*)d_out;
  float* M   = (float*)d_ws;  // B * 32 * 64 floats = 33.5 MB

  const int B = in_sizes[0] / 32;  // 4096
  const int T = in_sizes[1] / 32;  // 204800

  precompute_M<<<B / 16, 256, 0, stream>>>(cand, W1, M);
  attention_rows<<<B, 256, 0, stream>>>(cand, behavior, row_ids, W1, b1, alpha,
                                        W2, b2, M, out, T);
}